// Round 1
// baseline (358.745 us; speedup 1.0000x reference)
//
#include <hip/hip_runtime.h>
#include <hip/hip_bf16.h>
#include <cstdint>

typedef __attribute__((ext_vector_type(8))) short short8;
typedef __attribute__((ext_vector_type(4))) float f32x4;

#define DEV static __device__ __forceinline__

DEV f32x4 mfma16(short8 a, short8 b, f32x4 c) {
    return __builtin_amdgcn_mfma_f32_16x16x32_bf16(a, b, c, 0, 0, 0);
}

DEV unsigned short f2bf(float f) {
    __hip_bfloat16 h = __float2bfloat16(f);
    return __builtin_bit_cast(unsigned short, h);
}

// global -> LDS direct load, 16B per lane. Dest: wave-uniform base + lane*16.
#define GLOAD16(gp, lp)                                                        \
    __builtin_amdgcn_global_load_lds(                                          \
        (const __attribute__((address_space(1))) unsigned int*)(uintptr_t)(gp),\
        (__attribute__((address_space(3))) unsigned int*)(uintptr_t)(lp),      \
        16, 0, 0)

// ---------------- prep kernels ----------------

__global__ void pe_kernel(float* __restrict__ pe) {
    int i = threadIdx.x;
    if (i >= 512) return;
    float div = expf((float)(2 * i) * (-9.210340371976184f / 1024.0f));
    pe[2 * i]          = 0.0f;      // sin(0*div)
    pe[2 * i + 1]      = 1.0f;      // cos(0*div)
    pe[1024 + 2 * i]     = sinf(div);
    pe[1024 + 2 * i + 1] = cosf(div);
}

__global__ void cvt_bf16(const float* __restrict__ src, unsigned short* __restrict__ dst, int n4) {
    int stride = gridDim.x * blockDim.x;
    for (int i = blockIdx.x * blockDim.x + threadIdx.x; i < n4; i += stride) {
        float4 v = ((const float4*)src)[i];
        ushort4 o;
        o.x = f2bf(v.x); o.y = f2bf(v.y); o.z = f2bf(v.z); o.w = f2bf(v.w);
        ((ushort4*)dst)[i] = o;
    }
}

// mask [2048,2048] int32 (0/1) -> bit-words [2048][64]
__global__ void pack_mask(const int* __restrict__ mask, unsigned int* __restrict__ words) {
    int w = blockIdx.x * blockDim.x + threadIdx.x;   // 0..131071
    const int4* m4 = (const int4*)mask + (size_t)w * 8;
    unsigned int bits = 0;
#pragma unroll
    for (int j = 0; j < 8; j++) {
        int4 v = m4[j];
        bits |= (unsigned)(v.x & 1) << (4 * j);
        bits |= (unsigned)(v.y & 1) << (4 * j + 1);
        bits |= (unsigned)(v.z & 1) << (4 * j + 2);
        bits |= (unsigned)(v.w & 1) << (4 * j + 3);
    }
    words[w] = bits;
}

// ---------------- GEMM mainloop (128x128 tile, BK=32, 4 waves 2x2, K=1024) ----------------
// A: [M,1024] bf16 row-major; Bm: [N,1024] bf16 row-major (B^T form).
DEV void gemm_mainloop(const unsigned short* __restrict__ A,
                       const unsigned short* __restrict__ Bm,
                       int m0, int n0, f32x4 (&acc)[4][4],
                       unsigned short* As, unsigned short* Bs) {
    const int t = threadIdx.x;
    const int w = t >> 6;
    const int l = t & 63, lr = l & 15, lg = l >> 4;
    const int wr = w >> 1, wc = w & 1;
    const int srow = t >> 2;            // staging row 0..63
    const int scol = (t & 3) * 8;       // staging col (elements)
#pragma unroll
    for (int i = 0; i < 4; i++)
#pragma unroll
        for (int j = 0; j < 4; j++) acc[i][j] = f32x4{0.f, 0.f, 0.f, 0.f};

    const unsigned short* Ap = A + (size_t)(m0 + srow) * 1024 + scol;
    const unsigned short* Bp = Bm + (size_t)(n0 + srow) * 1024 + scol;
    unsigned short* dA = As + w * 512;  // wave-uniform LDS dest
    unsigned short* dB = Bs + w * 512;

    for (int k0 = 0; k0 < 1024; k0 += 32) {
        GLOAD16(Ap + k0, dA);
        GLOAD16(Ap + 64 * 1024 + k0, dA + 2048);
        GLOAD16(Bp + k0, dB);
        GLOAD16(Bp + 64 * 1024 + k0, dB + 2048);
        __syncthreads();   // drains vmcnt: LDS tiles ready
        short8 af[4], bfr[4];
#pragma unroll
        for (int i = 0; i < 4; i++)
            af[i] = *(const short8*)(As + (wr * 64 + i * 16 + lr) * 32 + lg * 8);
#pragma unroll
        for (int j = 0; j < 4; j++)
            bfr[j] = *(const short8*)(Bs + (wc * 64 + j * 16 + lr) * 32 + lg * 8);
#pragma unroll
        for (int i = 0; i < 4; i++)
#pragma unroll
            for (int j = 0; j < 4; j++)
                acc[i][j] = mfma16(af[i], bfr[j], acc[i][j]);
        __syncthreads();   // reads done before next stage overwrites
    }
}

// qkv GEMM: M=4096 (b*2048+s), N=3072. Epilogue: +bias, +pe (q,k), q*=1/8,
// scatter q,k -> [B,H,S,64] bf16; v -> vt [B,H,64,S] bf16.
__global__ __launch_bounds__(256) void qkv_gemm(
    const unsigned short* __restrict__ x, const unsigned short* __restrict__ wq,
    const float* __restrict__ bias, const float* __restrict__ pe,
    unsigned short* __restrict__ qo, unsigned short* __restrict__ ko,
    unsigned short* __restrict__ vt) {
    __shared__ unsigned short As[128 * 32], Bs[128 * 32];
    const int m0 = blockIdx.y * 128, n0 = blockIdx.x * 128;
    f32x4 acc[4][4];
    gemm_mainloop(x, wq, m0, n0, acc, As, Bs);

    const int t = threadIdx.x, w = t >> 6, l = t & 63;
    const int wr = w >> 1, wc = w & 1, lr = l & 15, lg = l >> 4;
#pragma unroll
    for (int i = 0; i < 4; i++) {
#pragma unroll
        for (int j = 0; j < 4; j++) {
            const int n = n0 + wc * 64 + j * 16 + lr;
            const int part = n >> 10, d = n & 1023, h = d >> 6, hd = d & 63;
            const float bia = bias[n];
#pragma unroll
            for (int r = 0; r < 4; r++) {
                const int m = m0 + wr * 64 + i * 16 + lg * 4 + r;
                const int b = m >> 11, s = m & 2047;
                float v = acc[i][j][r] + bia;
                if (part == 0) {
                    v = (v + pe[b * 1024 + d]) * 0.125f;   // fold 1/sqrt(64)
                    qo[((size_t)(b * 16 + h) * 2048 + s) * 64 + hd] = f2bf(v);
                } else if (part == 1) {
                    v += pe[b * 1024 + d];
                    ko[((size_t)(b * 16 + h) * 2048 + s) * 64 + hd] = f2bf(v);
                } else {
                    vt[((size_t)(b * 16 + h) * 64 + hd) * 2048 + s] = f2bf(v);
                }
            }
        }
    }
}

// fc GEMM: M=4096, N=1024, out f32 += fc_b
__global__ __launch_bounds__(256) void fc_gemm(
    const unsigned short* __restrict__ a, const unsigned short* __restrict__ wf,
    const float* __restrict__ bias, float* __restrict__ out) {
    __shared__ unsigned short As[128 * 32], Bs[128 * 32];
    const int m0 = blockIdx.y * 128, n0 = blockIdx.x * 128;
    f32x4 acc[4][4];
    gemm_mainloop(a, wf, m0, n0, acc, As, Bs);

    const int t = threadIdx.x, w = t >> 6, l = t & 63;
    const int wr = w >> 1, wc = w & 1, lr = l & 15, lg = l >> 4;
#pragma unroll
    for (int i = 0; i < 4; i++) {
#pragma unroll
        for (int j = 0; j < 4; j++) {
            const int n = n0 + wc * 64 + j * 16 + lr;
            const float bia = bias[n];
#pragma unroll
            for (int r = 0; r < 4; r++) {
                const int m = m0 + wr * 64 + i * 16 + lg * 4 + r;
                out[(size_t)m * 1024 + n] = acc[i][j][r] + bia;
            }
        }
    }
}

// ---------------- flash attention ----------------
// grid (32 qblocks, 16 heads, 2 batch), 256 thr = 4 waves, each wave 16 q-rows.
// q pre-scaled by 1/8. KBLK=32 keys/iter. mask: packed bits (1 => -1e9).
__global__ __launch_bounds__(256) void attn(
    const unsigned short* __restrict__ q, const unsigned short* __restrict__ k,
    const unsigned short* __restrict__ vt, const unsigned int* __restrict__ mw,
    unsigned short* __restrict__ ao) {
    __shared__ unsigned short P[4][16 * 40];   // per-wave P tile, row stride 40 (80B, 16B-aligned)
    const int t = threadIdx.x, w = t >> 6, l = t & 63, lr = l & 15, lg = l >> 4;
    const int qb = blockIdx.x, h = blockIdx.y, b = blockIdx.z;
    const int bh = b * 16 + h;
    const int q0 = qb * 64 + w * 16;
    const unsigned short* qbase = q + (size_t)bh * 2048 * 64;
    const unsigned short* kbase = k + (size_t)bh * 2048 * 64;
    const unsigned short* vbase = vt + (size_t)bh * 64 * 2048;
    unsigned short* Pw = P[w];
    const float L2E = 1.4426950408889634f;

    short8 qa[2];
    qa[0] = *(const short8*)(qbase + (q0 + lr) * 64 + lg * 8);
    qa[1] = *(const short8*)(qbase + (q0 + lr) * 64 + 32 + lg * 8);

    f32x4 O[4];
#pragma unroll
    for (int df = 0; df < 4; df++) O[df] = f32x4{0.f, 0.f, 0.f, 0.f};
    float mrow[4], lrow[4];
#pragma unroll
    for (int r = 0; r < 4; r++) { mrow[r] = -INFINITY; lrow[r] = 0.f; }

    for (int kb = 0; kb < 64; kb++) {
        // scores: two 16-key subtiles, accumulate over d=64 (2 MFMAs each)
        f32x4 sc[2];
#pragma unroll
        for (int ks = 0; ks < 2; ks++) {
            const unsigned short* kp = kbase + (kb * 32 + ks * 16 + lr) * 64 + lg * 8;
            short8 k0 = *(const short8*)kp;
            short8 k1 = *(const short8*)(kp + 32);
            f32x4 z = f32x4{0.f, 0.f, 0.f, 0.f};
            z = mfma16(qa[0], k0, z);
            z = mfma16(qa[1], k1, z);
            sc[ks] = z;
        }
        // mask (bit==1 -> -1e9), C-layout: col=lane&15, row=(lane>>4)*4+r
#pragma unroll
        for (int r = 0; r < 4; r++) {
            unsigned int wd = mw[(q0 + lg * 4 + r) * 64 + kb];
            if ((wd >> lr) & 1u)        sc[0][r] = -1e9f;
            if ((wd >> (16 + lr)) & 1u) sc[1][r] = -1e9f;
        }
        // online softmax (row stats via 16-lane xor-shuffle reduce)
        float al[4];
#pragma unroll
        for (int r = 0; r < 4; r++) {
            float mx = fmaxf(sc[0][r], sc[1][r]);
            mx = fmaxf(mx, __shfl_xor(mx, 1));
            mx = fmaxf(mx, __shfl_xor(mx, 2));
            mx = fmaxf(mx, __shfl_xor(mx, 4));
            mx = fmaxf(mx, __shfl_xor(mx, 8));
            float mn = fmaxf(mrow[r], mx);
            float a = exp2f((mrow[r] - mn) * L2E);
            mrow[r] = mn;
            float p0 = exp2f((sc[0][r] - mn) * L2E);
            float p1 = exp2f((sc[1][r] - mn) * L2E);
            sc[0][r] = p0; sc[1][r] = p1;
            float rs = p0 + p1;
            rs += __shfl_xor(rs, 1);
            rs += __shfl_xor(rs, 2);
            rs += __shfl_xor(rs, 4);
            rs += __shfl_xor(rs, 8);
            lrow[r] = lrow[r] * a + rs;
            al[r] = a;
        }
#pragma unroll
        for (int df = 0; df < 4; df++)
#pragma unroll
            for (int r = 0; r < 4; r++) O[df][r] *= al[r];
        // P (C-layout) -> LDS -> A-frag layout
#pragma unroll
        for (int r = 0; r < 4; r++) {
            Pw[(lg * 4 + r) * 40 + lr]      = f2bf(sc[0][r]);
            Pw[(lg * 4 + r) * 40 + 16 + lr] = f2bf(sc[1][r]);
        }
        short8 pa = *(const short8*)(Pw + lr * 40 + lg * 8);
        // PV: O[16q x 16d] x4, V B-operand from vt rows (B^T form)
#pragma unroll
        for (int df = 0; df < 4; df++) {
            short8 vf = *(const short8*)(vbase + (df * 16 + lr) * 2048 + kb * 32 + lg * 8);
            O[df] = mfma16(pa, vf, O[df]);
        }
    }
    // finalize + write attn_out [4096,1024] bf16
#pragma unroll
    for (int r = 0; r < 4; r++) {
        float inv = 1.0f / lrow[r];
#pragma unroll
        for (int df = 0; df < 4; df++) O[df][r] *= inv;
    }
#pragma unroll
    for (int df = 0; df < 4; df++)
#pragma unroll
        for (int r = 0; r < 4; r++) {
            int s = q0 + lg * 4 + r;
            int col = h * 64 + df * 16 + lr;
            ao[((size_t)(b * 2048 + s)) * 1024 + col] = f2bf(O[df][r]);
        }
}

// ---------------- launcher ----------------
extern "C" void kernel_launch(void* const* d_in, const int* in_sizes, int n_in,
                              void* d_out, int out_size, void* d_ws, size_t ws_size,
                              hipStream_t stream) {
    const float* x     = (const float*)d_in[0];
    const int*   mask  = (const int*)d_in[1];
    const float* qkv_w = (const float*)d_in[2];
    const float* qkv_b = (const float*)d_in[3];
    const float* fc_w  = (const float*)d_in[4];
    const float* fc_b  = (const float*)d_in[5];
    float* out = (float*)d_out;

    char* ws = (char*)d_ws;
    size_t off = 0;
    auto alloc = [&](size_t bytes) {
        off = (off + 255) & ~(size_t)255;
        void* p = ws + off;
        off += bytes;
        return p;
    };
    float*          pe     = (float*)alloc(2 * 1024 * 4);
    unsigned int*   mwords = (unsigned int*)alloc((size_t)2048 * 64 * 4);
    unsigned short* xb     = (unsigned short*)alloc((size_t)4096 * 1024 * 2);
    unsigned short* wqkv   = (unsigned short*)alloc((size_t)3072 * 1024 * 2);
    unsigned short* wfc    = (unsigned short*)alloc((size_t)1024 * 1024 * 2);
    unsigned short* qb16   = (unsigned short*)alloc((size_t)2 * 16 * 2048 * 64 * 2);
    unsigned short* kb16   = (unsigned short*)alloc((size_t)2 * 16 * 2048 * 64 * 2);
    unsigned short* vtb    = (unsigned short*)alloc((size_t)2 * 16 * 64 * 2048 * 2);
    unsigned short* attn_o = (unsigned short*)alloc((size_t)4096 * 1024 * 2);

    pe_kernel<<<1, 512, 0, stream>>>(pe);
    cvt_bf16<<<1024, 256, 0, stream>>>(x, xb, 4096 * 1024 / 4);
    cvt_bf16<<<768, 256, 0, stream>>>(qkv_w, wqkv, 3072 * 1024 / 4);
    cvt_bf16<<<256, 256, 0, stream>>>(fc_w, wfc, 1024 * 1024 / 4);
    pack_mask<<<512, 256, 0, stream>>>(mask, mwords);
    qkv_gemm<<<dim3(24, 32), 256, 0, stream>>>(xb, wqkv, qkv_b, pe, qb16, kb16, vtb);
    attn<<<dim3(32, 16, 2), 256, 0, stream>>>(qb16, kb16, vtb, mwords, attn_o);
    fc_gemm<<<dim3(8, 32), 256, 0, stream>>>(attn_o, wfc, fc_b, out);
}